// Round 5
// baseline (88.918 us; speedup 1.0000x reference)
//
#include <hip/hip_runtime.h>

#define Bn 32
#define Cn 256
#define HWn 3136          // 56*56
#define HW4 784           // HWn/4 = 64*12 + 16
#define NTHREADS 256

typedef float f4 __attribute__((ext_vector_type(4)));

__device__ __forceinline__ float dot4(f4 a, f4 b) {
  return a.x * b.x + a.y * b.y + a.z * b.z + a.w * b.w;
}

#define NTLD(p) __builtin_nontemporal_load(p)

// ---------------------------------------------------------------------------
// K1: one wave per (b,c) plane; 2048 blocks x 256 thr = 8192 waves.
// __launch_bounds__(256,4): min 4 waves/EU -> VGPR cap 128, so the compiler
// can hold two 12-float4 stage buffers (A/B software pipeline) + tail in
// registers. ~24 loads in flight per wave instead of ~2 (VGPR=32 last round).
// cg/dg single-use -> nontemporal (preserve L3 for x; K3 re-reads x).
// ---------------------------------------------------------------------------
__global__ __launch_bounds__(NTHREADS, 4) void importance_kernel(
    const float* __restrict__ x, const float* __restrict__ cg,
    const float* __restrict__ dg, float* __restrict__ cim,
    float* __restrict__ dimv) {
  const int lane = threadIdx.x & 63;
  const int bc = (blockIdx.x << 2) | (threadIdx.x >> 6);  // plane id 0..8191
  const size_t base = (size_t)bc * HWn;
  const f4* __restrict__ xp = (const f4*)(x + base);
  const f4* __restrict__ cp = (const f4*)(cg + base);
  const f4* __restrict__ dp = (const f4*)(dg + base);

  // tail (f4 indices 768..783, lanes 0..15) issued first so latency overlaps
  f4 xt = {0.f, 0.f, 0.f, 0.f}, ct = xt, dt = xt;
  const bool has_tail = (lane < 16);
  if (has_tail) {
    xt = xp[768 + lane];
    ct = NTLD(cp + 768 + lane);
    dt = NTLD(dp + 768 + lane);
  }

  // stage 0 -> A  (f4 indices lane+0,64,128,192)
  f4 xa0 = xp[lane +   0], xa1 = xp[lane +  64], xa2 = xp[lane + 128], xa3 = xp[lane + 192];
  f4 ca0 = NTLD(cp + lane +   0), ca1 = NTLD(cp + lane +  64),
     ca2 = NTLD(cp + lane + 128), ca3 = NTLD(cp + lane + 192);
  f4 da0 = NTLD(dp + lane +   0), da1 = NTLD(dp + lane +  64),
     da2 = NTLD(dp + lane + 128), da3 = NTLD(dp + lane + 192);

  // stage 1 -> B  (f4 indices lane+256..448)
  f4 xb0 = xp[lane + 256], xb1 = xp[lane + 320], xb2 = xp[lane + 384], xb3 = xp[lane + 448];
  f4 cb0 = NTLD(cp + lane + 256), cb1 = NTLD(cp + lane + 320),
     cb2 = NTLD(cp + lane + 384), cb3 = NTLD(cp + lane + 448);
  f4 db0 = NTLD(dp + lane + 256), db1 = NTLD(dp + lane + 320),
     db2 = NTLD(dp + lane + 384), db3 = NTLD(dp + lane + 448);

  // consume stage 0 (A)
  float accC = dot4(xa0, ca0) + dot4(xa1, ca1) + dot4(xa2, ca2) + dot4(xa3, ca3);
  float accD = dot4(xa0, da0) + dot4(xa1, da1) + dot4(xa2, da2) + dot4(xa3, da3);

  // stage 2 -> A regs reused  (f4 indices lane+512..704)
  xa0 = xp[lane + 512]; xa1 = xp[lane + 576]; xa2 = xp[lane + 640]; xa3 = xp[lane + 704];
  ca0 = NTLD(cp + lane + 512); ca1 = NTLD(cp + lane + 576);
  ca2 = NTLD(cp + lane + 640); ca3 = NTLD(cp + lane + 704);
  da0 = NTLD(dp + lane + 512); da1 = NTLD(dp + lane + 576);
  da2 = NTLD(dp + lane + 640); da3 = NTLD(dp + lane + 704);

  // consume stage 1 (B)
  accC += dot4(xb0, cb0) + dot4(xb1, cb1) + dot4(xb2, cb2) + dot4(xb3, cb3);
  accD += dot4(xb0, db0) + dot4(xb1, db1) + dot4(xb2, db2) + dot4(xb3, db3);

  // consume stage 2 (A)
  accC += dot4(xa0, ca0) + dot4(xa1, ca1) + dot4(xa2, ca2) + dot4(xa3, ca3);
  accD += dot4(xa0, da0) + dot4(xa1, da1) + dot4(xa2, da2) + dot4(xa3, da3);

  // tail
  accC += dot4(xt, ct);
  accD += dot4(xt, dt);

  // wave-local reduce (64 lanes)
  for (int off = 32; off; off >>= 1) {
    accC += __shfl_down(accC, off);
    accD += __shfl_down(accD, off);
  }
  if (lane == 0) {
    cim[bc] = accC * (1.0f / HWn);
    dimv[bc] = accD * (1.0f / HWn);
  }
}

// ---------------------------------------------------------------------------
// K2: per-sample quantile thresholds (rank selection over 256 channels) and
// mask generation: m1 = cs&ds, m2 = (!cs)&ds, mdi = !ds
// quantile(0.5): pos = 127.5 -> 0.5*(s127+s128); quantile(0.8): pos=204 -> s204
// ---------------------------------------------------------------------------
__global__ __launch_bounds__(NTHREADS) void quantile_mask_kernel(
    const float* __restrict__ cim, const float* __restrict__ dimv,
    float* __restrict__ m1, float* __restrict__ m2, float* __restrict__ mdi) {
  const int b = blockIdx.x;
  const int c = threadIdx.x;
  __shared__ float sc[Cn], sd[Cn];
  __shared__ float q127, q128, q204;
  const float v = cim[b * Cn + c];
  const float w = dimv[b * Cn + c];
  sc[c] = v;
  sd[c] = w;
  __syncthreads();

  int cl = 0, ce = 0, dl = 0, de = 0;
  for (int j = 0; j < Cn; ++j) {
    float u = sc[j];
    cl += (u < v);
    ce += (u == v);
    float t = sd[j];
    dl += (t < w);
    de += (t == w);
  }
  if (cl <= 127 && 127 < cl + ce) q127 = v;
  if (cl <= 128 && 128 < cl + ce) q128 = v;
  if (dl <= 204 && 204 < dl + de) q204 = w;
  __syncthreads();

  const float cthr = 0.5f * (q127 + q128);
  const float dthr = q204;
  const bool cs = v > cthr;
  const bool ds = w > dthr;
  m1[b * Cn + c] = (cs && ds) ? 1.f : 0.f;
  m2[b * Cn + c] = (!cs && ds) ? 1.f : 0.f;
  mdi[b * Cn + c] = ds ? 0.f : 1.f;
}

// ---------------------------------------------------------------------------
// K3: out[b,c,:] = A*x[b,c,:] + B1*x[sb,c,:] + B2*x[db,c,:]
// x reads come mostly from L3; out never read back -> nontemporal stores.
// ---------------------------------------------------------------------------
__global__ __launch_bounds__(NTHREADS) void mix_kernel(
    const float* __restrict__ x, const float* __restrict__ ms,
    const int* __restrict__ same_idx, const int* __restrict__ diff_idx,
    const float* __restrict__ m1, const float* __restrict__ m2,
    const float* __restrict__ mdi, float* __restrict__ out) {
  const int bc = blockIdx.x;
  const int b = bc >> 8;
  const int c = bc & 255;
  const int sb = same_idx[b];
  const int db = diff_idx[b];
  const float s0 = ms[b * 2 + 0];
  const float s1 = ms[b * 2 + 1];

  const float A = mdi[bc] + s0 * m1[bc] + s1 * m2[bc];
  const float B1 = (1.f - s0) * m1[sb * Cn + c];
  const float B2 = (1.f - s1) * m2[db * Cn + c];

  const f4* __restrict__ xp = (const f4*)(x + (size_t)bc * HWn);
  const f4* __restrict__ xs = (const f4*)(x + ((size_t)sb * Cn + c) * HWn);
  const f4* __restrict__ xd = (const f4*)(x + ((size_t)db * Cn + c) * HWn);
  f4* __restrict__ op = (f4*)(out + (size_t)bc * HWn);

  const bool u1 = (B1 != 0.f);
  const bool u2 = (B2 != 0.f);
  const int t = threadIdx.x;

  f4 r0, r1, r2;
  {
    f4 xv0 = xp[t];
    f4 xv1 = xp[t + 256];
    f4 xv2 = xp[t + 512];
    r0 = A * xv0;
    r1 = A * xv1;
    r2 = A * xv2;
  }
  if (u1) {
    f4 s0v = xs[t];
    f4 s1v = xs[t + 256];
    f4 s2v = xs[t + 512];
    r0 += B1 * s0v;
    r1 += B1 * s1v;
    r2 += B1 * s2v;
  }
  if (u2) {
    f4 d0v = xd[t];
    f4 d1v = xd[t + 256];
    f4 d2v = xd[t + 512];
    r0 += B2 * d0v;
    r1 += B2 * d1v;
    r2 += B2 * d2v;
  }
  __builtin_nontemporal_store(r0, op + t);
  __builtin_nontemporal_store(r1, op + t + 256);
  __builtin_nontemporal_store(r2, op + t + 512);

  if (t < 16) {
    f4 xv3 = xp[768 + t];
    f4 r3 = A * xv3;
    if (u1) {
      f4 s3v = xs[768 + t];
      r3 += B1 * s3v;
    }
    if (u2) {
      f4 d3v = xd[768 + t];
      r3 += B2 * d3v;
    }
    __builtin_nontemporal_store(r3, op + 768 + t);
  }
}

extern "C" void kernel_launch(void* const* d_in, const int* in_sizes, int n_in,
                              void* d_out, int out_size, void* d_ws, size_t ws_size,
                              hipStream_t stream) {
  const float* x  = (const float*)d_in[0];
  const float* cg = (const float*)d_in[1];
  const float* dg = (const float*)d_in[2];
  const float* ms = (const float*)d_in[3];
  // d_in[4] = y, d_in[5] = domain (unused: index pickers precomputed)
  const int* same_idx = (const int*)d_in[6];
  const int* diff_idx = (const int*)d_in[7];
  float* out = (float*)d_out;

  float* ws = (float*)d_ws;
  float* cim  = ws;                // B*C
  float* dimv = ws + Bn * Cn;      // B*C
  float* m1   = ws + 2 * Bn * Cn;  // B*C
  float* m2   = ws + 3 * Bn * Cn;  // B*C
  float* mdi  = ws + 4 * Bn * Cn;  // B*C

  importance_kernel<<<(Bn * Cn) / 4, NTHREADS, 0, stream>>>(x, cg, dg, cim, dimv);
  quantile_mask_kernel<<<Bn, NTHREADS, 0, stream>>>(cim, dimv, m1, m2, mdi);
  mix_kernel<<<Bn * Cn, NTHREADS, 0, stream>>>(x, ms, same_idx, diff_idx, m1, m2, mdi, out);
}

// Round 6
// 88.661 us; speedup vs baseline: 1.0029x; 1.0029x over previous
//
#include <hip/hip_runtime.h>

#define Bn 32
#define Cn 256
#define HWn 3136          // 56*56
#define HW4 784           // HWn/4 = 64*12 + 16
#define NTHREADS 256

typedef float f4 __attribute__((ext_vector_type(4)));

__device__ __forceinline__ float dot4(f4 a, f4 b) {
  return a.x * b.x + a.y * b.y + a.z * b.z + a.w * b.w;
}

#define NTLD(p) __builtin_nontemporal_load(p)
#define SB() __builtin_amdgcn_sched_barrier(0)

// ---------------------------------------------------------------------------
// K1: one wave per (b,c) plane; 2048 blocks x 256 thr = 8192 waves.
// The pre-RA scheduler collapsed every previous software pipeline back to
// VGPR=32 / ~2 loads in flight. This version pins the pipeline with
// sched_barrier(0) fences: 27 f4 loads issued before the first fence, 12 more
// issued alongside stage-0 consumption. Live set ~110 VGPR forces deep MLP.
// cg/dg single-use -> nontemporal (preserve L3 for x; K3 re-reads x).
// ---------------------------------------------------------------------------
__global__ __launch_bounds__(NTHREADS, 2) void importance_kernel(
    const float* __restrict__ x, const float* __restrict__ cg,
    const float* __restrict__ dg, float* __restrict__ cim,
    float* __restrict__ dimv) {
  const int lane = threadIdx.x & 63;
  const int bc = (blockIdx.x << 2) | (threadIdx.x >> 6);  // plane id 0..8191
  const size_t base = (size_t)bc * HWn;
  const f4* __restrict__ xp = (const f4*)(x + base);
  const f4* __restrict__ cp = (const f4*)(cg + base);
  const f4* __restrict__ dp = (const f4*)(dg + base);

  // ---- region 1: issue tail + stage0 + stage1 loads (27 f4 per thread) ----
  f4 xt = {0.f, 0.f, 0.f, 0.f}, ct = xt, dt = xt;
  if (lane < 16) {
    xt = xp[768 + lane];
    ct = NTLD(cp + 768 + lane);
    dt = NTLD(dp + 768 + lane);
  }
  f4 xa0 = xp[lane +   0], xa1 = xp[lane +  64], xa2 = xp[lane + 128], xa3 = xp[lane + 192];
  f4 ca0 = NTLD(cp + lane +   0), ca1 = NTLD(cp + lane +  64),
     ca2 = NTLD(cp + lane + 128), ca3 = NTLD(cp + lane + 192);
  f4 da0 = NTLD(dp + lane +   0), da1 = NTLD(dp + lane +  64),
     da2 = NTLD(dp + lane + 128), da3 = NTLD(dp + lane + 192);

  f4 xb0 = xp[lane + 256], xb1 = xp[lane + 320], xb2 = xp[lane + 384], xb3 = xp[lane + 448];
  f4 cb0 = NTLD(cp + lane + 256), cb1 = NTLD(cp + lane + 320),
     cb2 = NTLD(cp + lane + 384), cb3 = NTLD(cp + lane + 448);
  f4 db0 = NTLD(dp + lane + 256), db1 = NTLD(dp + lane + 320),
     db2 = NTLD(dp + lane + 384), db3 = NTLD(dp + lane + 448);
  SB();

  // ---- region 2: consume stage0, issue stage2 loads (12 f4) ----
  float accC = dot4(xa0, ca0) + dot4(xa1, ca1) + dot4(xa2, ca2) + dot4(xa3, ca3);
  float accD = dot4(xa0, da0) + dot4(xa1, da1) + dot4(xa2, da2) + dot4(xa3, da3);
  f4 xc0 = xp[lane + 512], xc1 = xp[lane + 576], xc2 = xp[lane + 640], xc3 = xp[lane + 704];
  f4 cc0 = NTLD(cp + lane + 512), cc1 = NTLD(cp + lane + 576),
     cc2 = NTLD(cp + lane + 640), cc3 = NTLD(cp + lane + 704);
  f4 dc0 = NTLD(dp + lane + 512), dc1 = NTLD(dp + lane + 576),
     dc2 = NTLD(dp + lane + 640), dc3 = NTLD(dp + lane + 704);
  SB();

  // ---- region 3: consume stage1 ----
  accC += dot4(xb0, cb0) + dot4(xb1, cb1) + dot4(xb2, cb2) + dot4(xb3, cb3);
  accD += dot4(xb0, db0) + dot4(xb1, db1) + dot4(xb2, db2) + dot4(xb3, db3);
  SB();

  // ---- region 4: consume stage2 + tail ----
  accC += dot4(xc0, cc0) + dot4(xc1, cc1) + dot4(xc2, cc2) + dot4(xc3, cc3);
  accD += dot4(xc0, dc0) + dot4(xc1, dc1) + dot4(xc2, dc2) + dot4(xc3, dc3);
  accC += dot4(xt, ct);
  accD += dot4(xt, dt);

  // wave-local reduce (64 lanes)
  for (int off = 32; off; off >>= 1) {
    accC += __shfl_down(accC, off);
    accD += __shfl_down(accD, off);
  }
  if (lane == 0) {
    cim[bc] = accC * (1.0f / HWn);
    dimv[bc] = accD * (1.0f / HWn);
  }
}

// ---------------------------------------------------------------------------
// K2: per-sample quantile thresholds (rank selection over 256 channels) and
// mask generation: m1 = cs&ds, m2 = (!cs)&ds, mdi = !ds
// quantile(0.5): pos = 127.5 -> 0.5*(s127+s128); quantile(0.8): pos=204 -> s204
// ---------------------------------------------------------------------------
__global__ __launch_bounds__(NTHREADS) void quantile_mask_kernel(
    const float* __restrict__ cim, const float* __restrict__ dimv,
    float* __restrict__ m1, float* __restrict__ m2, float* __restrict__ mdi) {
  const int b = blockIdx.x;
  const int c = threadIdx.x;
  __shared__ float sc[Cn], sd[Cn];
  __shared__ float q127, q128, q204;
  const float v = cim[b * Cn + c];
  const float w = dimv[b * Cn + c];
  sc[c] = v;
  sd[c] = w;
  __syncthreads();

  int cl = 0, ce = 0, dl = 0, de = 0;
  for (int j = 0; j < Cn; ++j) {
    float u = sc[j];
    cl += (u < v);
    ce += (u == v);
    float t = sd[j];
    dl += (t < w);
    de += (t == w);
  }
  if (cl <= 127 && 127 < cl + ce) q127 = v;
  if (cl <= 128 && 128 < cl + ce) q128 = v;
  if (dl <= 204 && 204 < dl + de) q204 = w;
  __syncthreads();

  const float cthr = 0.5f * (q127 + q128);
  const float dthr = q204;
  const bool cs = v > cthr;
  const bool ds = w > dthr;
  m1[b * Cn + c] = (cs && ds) ? 1.f : 0.f;
  m2[b * Cn + c] = (!cs && ds) ? 1.f : 0.f;
  mdi[b * Cn + c] = ds ? 0.f : 1.f;
}

// ---------------------------------------------------------------------------
// K3: out[b,c,:] = A*x[b,c,:] + B1*x[sb,c,:] + B2*x[db,c,:]
// x reads come mostly from L3; out never read back -> nontemporal stores.
// ---------------------------------------------------------------------------
__global__ __launch_bounds__(NTHREADS) void mix_kernel(
    const float* __restrict__ x, const float* __restrict__ ms,
    const int* __restrict__ same_idx, const int* __restrict__ diff_idx,
    const float* __restrict__ m1, const float* __restrict__ m2,
    const float* __restrict__ mdi, float* __restrict__ out) {
  const int bc = blockIdx.x;
  const int b = bc >> 8;
  const int c = bc & 255;
  const int sb = same_idx[b];
  const int db = diff_idx[b];
  const float s0 = ms[b * 2 + 0];
  const float s1 = ms[b * 2 + 1];

  const float A = mdi[bc] + s0 * m1[bc] + s1 * m2[bc];
  const float B1 = (1.f - s0) * m1[sb * Cn + c];
  const float B2 = (1.f - s1) * m2[db * Cn + c];

  const f4* __restrict__ xp = (const f4*)(x + (size_t)bc * HWn);
  const f4* __restrict__ xs = (const f4*)(x + ((size_t)sb * Cn + c) * HWn);
  const f4* __restrict__ xd = (const f4*)(x + ((size_t)db * Cn + c) * HWn);
  f4* __restrict__ op = (f4*)(out + (size_t)bc * HWn);

  const bool u1 = (B1 != 0.f);
  const bool u2 = (B2 != 0.f);
  const int t = threadIdx.x;

  f4 r0, r1, r2;
  {
    f4 xv0 = xp[t];
    f4 xv1 = xp[t + 256];
    f4 xv2 = xp[t + 512];
    r0 = A * xv0;
    r1 = A * xv1;
    r2 = A * xv2;
  }
  if (u1) {
    f4 s0v = xs[t];
    f4 s1v = xs[t + 256];
    f4 s2v = xs[t + 512];
    r0 += B1 * s0v;
    r1 += B1 * s1v;
    r2 += B1 * s2v;
  }
  if (u2) {
    f4 d0v = xd[t];
    f4 d1v = xd[t + 256];
    f4 d2v = xd[t + 512];
    r0 += B2 * d0v;
    r1 += B2 * d1v;
    r2 += B2 * d2v;
  }
  __builtin_nontemporal_store(r0, op + t);
  __builtin_nontemporal_store(r1, op + t + 256);
  __builtin_nontemporal_store(r2, op + t + 512);

  if (t < 16) {
    f4 xv3 = xp[768 + t];
    f4 r3 = A * xv3;
    if (u1) {
      f4 s3v = xs[768 + t];
      r3 += B1 * s3v;
    }
    if (u2) {
      f4 d3v = xd[768 + t];
      r3 += B2 * d3v;
    }
    __builtin_nontemporal_store(r3, op + 768 + t);
  }
}

extern "C" void kernel_launch(void* const* d_in, const int* in_sizes, int n_in,
                              void* d_out, int out_size, void* d_ws, size_t ws_size,
                              hipStream_t stream) {
  const float* x  = (const float*)d_in[0];
  const float* cg = (const float*)d_in[1];
  const float* dg = (const float*)d_in[2];
  const float* ms = (const float*)d_in[3];
  // d_in[4] = y, d_in[5] = domain (unused: index pickers precomputed)
  const int* same_idx = (const int*)d_in[6];
  const int* diff_idx = (const int*)d_in[7];
  float* out = (float*)d_out;

  float* ws = (float*)d_ws;
  float* cim  = ws;                // B*C
  float* dimv = ws + Bn * Cn;      // B*C
  float* m1   = ws + 2 * Bn * Cn;  // B*C
  float* m2   = ws + 3 * Bn * Cn;  // B*C
  float* mdi  = ws + 4 * Bn * Cn;  // B*C

  importance_kernel<<<(Bn * Cn) / 4, NTHREADS, 0, stream>>>(x, cg, dg, cim, dimv);
  quantile_mask_kernel<<<Bn, NTHREADS, 0, stream>>>(cim, dimv, m1, m2, mdi);
  mix_kernel<<<Bn * Cn, NTHREADS, 0, stream>>>(x, ms, same_idx, diff_idx, m1, m2, mdi, out);
}